// Round 5
// baseline (204.332 us; speedup 1.0000x reference)
//
#include <hip/hip_runtime.h>
#include <stdint.h>

typedef float f4 __attribute__((ext_vector_type(4)));
typedef float f32x4 __attribute__((ext_vector_type(4)));
typedef _Float16 hq4 __attribute__((ext_vector_type(4)));
typedef _Float16 half8 __attribute__((ext_vector_type(8)));

#define DF 128    // input feature dim
#define HID 64    // hidden dim
#define EPB 4096  // edges per sort block (391 sort blocks of 512 threads, 8/thread)
#define CAP 5120  // slots per coarse bucket (avg 4096, max~4314 for seed-0 input)

// ---------- fused: coarse bucket sort (blocks < nblk)  ||  g = x@W1 (rest) ----
// R21: gemm made independent of dinv (stores UNSCALED fp32 g; kB applies the
// dinv scale locally). Sort and GEMM have no data dependency -> one launch,
// GEMM hides under the sort's latency stalls. kPrep deleted (cur via memset,
// W1 repacked into LDS per GEMM block).
__global__ __launch_bounds__(512) void kFused(const int* __restrict__ row,
                                              const int* __restrict__ col,
                                              const float* __restrict__ ew,
                                              int* __restrict__ cur,
                                              int2* __restrict__ tmp,
                                              const float* __restrict__ x,
                                              const float* __restrict__ W1,
                                              float* __restrict__ g,
                                              int E, int nblk, int nstrip, int N) {
    __shared__ __align__(16) char smem[55360];   // union: sort 54.1KB / gemm 16KB
    int t = threadIdx.x;

    if ((int)blockIdx.x < nblk) {
        // ================= sort branch (R3-proven dataflow) =================
        int*  hist  = (int*)smem;                    // 512
        int*  pref  = hist + 512;                    // 512
        int*  lbase = pref + 512;                    // 512
        int*  wsum  = lbase + 512;                   // 8
        int2* sv    = (int2*)(smem + 6208);          // EPB int2 = 32 KB
        int*  sa    = (int*)(smem + 6208 + 32768);   // EPB int  = 16 KB
        int b = blockIdx.x;
        hist[t] = 0;
        __syncthreads();
        int s = b * EPB, e = min(E, s + EPB);
        int cnt = e - s;
        int  mybin[8], myrank[8];
        int2 myv[8];
#pragma unroll
        for (int k = 0; k < 8; ++k) {
            int i = s + t + k * 512;
            mybin[k] = -1;
            if (i < e) {
                int c = col[i];
                int bin = c >> 8;
                myv[k].x = row[i] | ((c & 255) << 24);   // src 17b | fine-col<<24
                myv[k].y = __float_as_int(ew[i]);
                mybin[k] = bin;
                myrank[k] = atomicAdd(&hist[bin], 1);
            }
        }
        __syncthreads();
        int val = hist[t];
        lbase[t] = val ? atomicAdd(&cur[t], val) + t * CAP : 0;  // absolute base
        int lane = t & 63, wid = t >> 6;
        int inc = val;
#pragma unroll
        for (int d = 1; d < 64; d <<= 1) {
            int y = __shfl_up(inc, d);
            if (lane >= d) inc += y;
        }
        if (lane == 63) wsum[wid] = inc;
        __syncthreads();
        if (t == 0) {
            int r = 0;
#pragma unroll
            for (int i = 0; i < 8; ++i) { int xx = wsum[i]; wsum[i] = r; r += xx; }
        }
        __syncthreads();
        pref[t] = inc - val + wsum[wid];   // exclusive prefix within block
        __syncthreads();
#pragma unroll
        for (int k = 0; k < 8; ++k) {
            if (mybin[k] >= 0) {
                int pos = pref[mybin[k]] + myrank[k];
                sv[pos] = myv[k];
                sa[pos] = lbase[mybin[k]] + myrank[k];
            }
        }
        __syncthreads();
        for (int i = t; i < cnt; i += 512) tmp[sa[i]] = sv[i];
    } else {
        // ================= GEMM branch: g = x @ W1 (fp32, unscaled) =========
        _Float16* W1f = (_Float16*)smem;             // 16 KB LDS B-fragments
        for (int i = t; i < 8192; i += 512) {
            int j     = i & 7;
            int lane  = (i >> 3) & 63;
            int ntile = (i >> 9) & 3;
            int kstep = i >> 11;
            int k = kstep * 32 + (lane >> 4) * 8 + j;
            int n = ntile * 16 + (lane & 15);
            W1f[i] = (_Float16)W1[k * 64 + n];
        }
        __syncthreads();
        int wave = ((int)blockIdx.x - nblk) * 8 + (t >> 6);
        if (wave >= nstrip) return;
        int node0 = wave << 4;
        int l = t & 63;
        int quad = l >> 4;
        int m = l & 15;
        int r = node0 + m;
        if (r >= N) r = N - 1;   // clamp (harmless duplicate load)

        const half8* bfrag = (const half8*)W1f;
        f32x4 acc[4];
#pragma unroll
        for (int nt = 0; nt < 4; ++nt) acc[nt] = (f32x4)(0.f);
#pragma unroll
        for (int kstep = 0; kstep < 4; ++kstep) {
            const f4* xr = (const f4*)(x + (size_t)r * DF + kstep * 32 + quad * 8);
            f4 a0 = xr[0], a1 = xr[1];
            half8 af;
            af[0] = (_Float16)a0.x; af[1] = (_Float16)a0.y;
            af[2] = (_Float16)a0.z; af[3] = (_Float16)a0.w;
            af[4] = (_Float16)a1.x; af[5] = (_Float16)a1.y;
            af[6] = (_Float16)a1.z; af[7] = (_Float16)a1.w;
#pragma unroll
            for (int nt = 0; nt < 4; ++nt) {
                half8 bf = bfrag[(kstep * 4 + nt) * 64 + l];
                acc[nt] = __builtin_amdgcn_mfma_f32_16x16x32_f16(af, bf, acc[nt], 0, 0, 0);
            }
        }
        int nodeb = node0 + quad * 4;
#pragma unroll
        for (int nt = 0; nt < 4; ++nt) {
#pragma unroll
            for (int reg = 0; reg < 4; ++reg) {
                int node = nodeb + reg;
                if (node < N)
                    g[(size_t)node * 64 + (unsigned)(nt * 16 + m)] = acc[nt][reg];
            }
        }
    }
}

// ---------- B: fine sort + dinv + h = fp16(dinv * g)  (single tmp read) --------
// R21: h-scale fused here (bucket's 256 nodes are block-local; dl[] holds di).
// fp16(di * g_fp32) is bit-identical to the old gemm1-side scaling.
__global__ __launch_bounds__(512) void kB(const int2* __restrict__ tmp,
                                          const int* __restrict__ cur,
                                          const float* __restrict__ g,
                                          int2* __restrict__ edata,
                                          int2* __restrict__ offse,
                                          float* __restrict__ dinv,
                                          _Float16* __restrict__ h,
                                          int N) {
    __shared__ int   hist[256];
    __shared__ float degl[256];
    __shared__ int   fill[256];
    __shared__ float dl[256];
    __shared__ int   wsum[8];
    __shared__ int2  se[CAP];   // 40 KB staged entries
    int bin = blockIdx.x, t = threadIdx.x;
    int s = bin * CAP;
    int cnt = min(cur[bin], CAP);

    if (t < 256) { hist[t] = 0; degl[t] = 0.f; }
    __syncthreads();
    for (int i = t; i < cnt; i += 512) {
        int2 pr = tmp[s + i];
        se[i] = pr;
        int lo = ((unsigned)pr.x) >> 24;
        atomicAdd(&hist[lo], 1);
        atomicAdd(&degl[lo], __int_as_float(pr.y));
    }
    __syncthreads();
    int val = (t < 256) ? hist[t] : 0;
    int lane = t & 63, wid = t >> 6;
    int inc = val;
#pragma unroll
    for (int d = 1; d < 64; d <<= 1) {
        int y = __shfl_up(inc, d);
        if (lane >= d) inc += y;
    }
    if (lane == 63) wsum[wid] = inc;
    __syncthreads();
    if (t == 0) {
        int r = 0;
#pragma unroll
        for (int i = 0; i < 8; ++i) { int x = wsum[i]; wsum[i] = r; r += x; }
    }
    __syncthreads();
    int pfx = inc - val + wsum[wid];   // exclusive prefix (valid for t<256)
    if (t < 256) {
        fill[t] = pfx;
        int c = bin * 256 + t;
        float di = 0.f;
        if (c < N) {
            int2 oe;
            oe.x = s + pfx;
            oe.y = s + pfx + val;
            offse[c] = oe;
            di = rsqrtf(1.0f + degl[t]);   // deg >= 1 (self-loop)
            dinv[c] = di;
        }
        dl[t] = di;
    }
    __syncthreads();
    // fine-sort scatter into the bucket's 40KB edata window (L2-absorbed)
    for (int i = t; i < cnt; i += 512) {
        int2 pr = se[i];
        int lo = ((unsigned)pr.x) >> 24;
        int pos = atomicAdd(&fill[lo], 1);
        int2 o;
        o.x = pr.x & 0x00FFFFFF;
        o.y = pr.y;
        edata[s + pos] = o;
    }
    // h = fp16(di * g) for this bucket's 256 nodes (fully coalesced)
    int vbase = bin << 8;
    for (int i = t; i < 256 * 64; i += 512) {
        int c = i >> 6;
        int v = vbase + c;
        if (v < N)
            h[(size_t)v * 64 + (i & 63)] =
                (_Float16)(dl[c] * g[(size_t)v * 64 + (i & 63)]);
    }
}

// ---------- fused layer-1 aggregate + relu + @W2 : FOUR nodes per wave ----------
// (proven R1 version: 16 lanes/node, lane-local aggregation, 16 gathers in
// flight/wave. R2's per-bucket LDS-atomic variant was 711us: TLP collapse.)
__global__ __launch_bounds__(256) void k_agg_h2(const int2* __restrict__ offse,
                                                const int2* __restrict__ edata,
                                                const float* __restrict__ dinv,
                                                const _Float16* __restrict__ h,
                                                const float* __restrict__ b1,
                                                const float* __restrict__ W2,
                                                float* __restrict__ h2p, int N) {
    __shared__ int2 stage[4][68];      // 4 waves x (4 groups x 17 padded) = 2176 B
    int wv = threadIdx.x >> 6;
    int l  = threadIdx.x & 63;
    int g  = l >> 4;                   // node group within wave (0..3)
    unsigned fq = (unsigned)(l & 15);  // feature quad: features 4fq..4fq+3
    int sbase = g * 17;                // padded LDS base for this group
    int vv = blockIdx.x * 16 + wv * 4 + g;
    bool ok = vv < N;
    int v = ok ? vv : N - 1;           // clamp (harmless duplicate work)
    const hq4* hp = (const hq4*)h;     // hp[(src<<4)|fq] = 4 features (8B)

    float di = dinv[v];
    int2 oe = offse[v];

    // self-loop: every lane holds its feature quad of h'[v]
    hq4 sv4 = hp[((unsigned)v << 4) | fq];
    float a0 = (float)sv4.x, a1 = (float)sv4.y;
    float a2 = (float)sv4.z, a3 = (float)sv4.w;

    int deg = oe.y - oe.x;
    for (int base = 0; base < deg; base += 16) {   // divergent only across groups
        int idx = oe.x + base + (int)fq;
        int2 pr;
        pr.x = 0; pr.y = 0;            // dummy: src 0, w = 0
        if (idx < oe.y) pr = edata[idx];
        stage[wv][sbase + (int)fq] = pr;   // wave-private row; no block barrier
#pragma unroll
        for (int k = 0; k < 16; ++k) {
            int2 em = stage[wv][sbase + k];   // 16-lane broadcast per group
            float w = __int_as_float(em.y);
            hq4 hv = hp[((unsigned)em.x << 4) | fq];
            a0 += w * (float)hv.x;
            a1 += w * (float)hv.y;
            a2 += w * (float)hv.z;
            a3 += w * (float)hv.w;
        }
    }

    a0 = di * a0; a1 = di * a1; a2 = di * a2; a3 = di * a3;
    f4 bb = ((const f4*)b1)[fq];
    f4 ww = ((const f4*)W2)[fq];
    float s = fmaxf(a0 + bb.x, 0.f) * ww.x
            + fmaxf(a1 + bb.y, 0.f) * ww.y
            + fmaxf(a2 + bb.z, 0.f) * ww.z
            + fmaxf(a3 + bb.w, 0.f) * ww.w;
    // reduce over the 16 feature-quad lanes (tree rooted at lane 16g)
    s += __shfl_down(s, 8);
    s += __shfl_down(s, 4);
    s += __shfl_down(s, 2);
    s += __shfl_down(s, 1);
    if (fq == 0 && ok) h2p[vv] = di * s;   // store dinv-scaled hidden
}

// ---------- layer-2 aggregation: 16 lanes per node; h2p pre-scaled ----------
__global__ __launch_bounds__(256) void k_out(const int2* __restrict__ offse,
                                             const int2* __restrict__ edata,
                                             const float* __restrict__ dinv,
                                             const float* __restrict__ h2p,
                                             const float* __restrict__ b2,
                                             float* __restrict__ out, int N) {
    int t = blockIdx.x * 256 + threadIdx.x;
    int v = t >> 4;
    if (v >= N) return;
    int c = t & 15;
    int2 oe = offse[v];
    float s = 0.f;
    for (int i = oe.x + c; i < oe.y; i += 16) {
        int2 pr = edata[i];
        s += __int_as_float(pr.y) * h2p[(unsigned)pr.x];
    }
    s += __shfl_down(s, 8);
    s += __shfl_down(s, 4);
    s += __shfl_down(s, 2);
    s += __shfl_down(s, 1);
    if (c == 0) {
        float di = dinv[v];
        out[v] = b2[0] + di * (h2p[v] + s);   // h2p[v] = di*h2[v]
    }
}

extern "C" void kernel_launch(void* const* d_in, const int* in_sizes, int n_in,
                              void* d_out, int out_size, void* d_ws, size_t ws_size,
                              hipStream_t stream) {
    const float* x  = (const float*)d_in[0];
    const int*   ei = (const int*)d_in[1];
    const float* ew = (const float*)d_in[2];
    const float* W1 = (const float*)d_in[3];
    const float* b1 = (const float*)d_in[4];
    const float* W2 = (const float*)d_in[5];
    const float* b2 = (const float*)d_in[6];
    float* out = (float*)d_out;

    const int N = in_sizes[0] / DF;       // 100000
    const int E = in_sizes[2];            // 1600000
    const int* row = ei;                  // sources
    const int* col = ei + E;              // targets

    const int nbin = (N + 255) / 256;     // 391 coarse buckets
    const int nblk = (E + EPB - 1) / EPB; // 391 sort blocks

    // ---- workspace layout, ~72 MB (memset shows budget >= 268 MB) ----
    size_t    gsz   = (size_t)nbin * CAP;                 // gapped entry count
    int2*     edata = (int2*)d_ws;                        // 16.0 MB
    int2*     tmp   = edata + gsz;                        // 16.0 MB
    float*    g     = (float*)(tmp + gsz);                // N*64 fp32 = 25.6 MB
    _Float16* h     = (_Float16*)(g + (size_t)N * 64);    // N*64 fp16 = 12.8 MB
    float*    dinv  = (float*)(h + (size_t)N * 64);       // N
    float*    h2p   = dinv + N;                           // N
    int2*     offse = (int2*)(h2p + N);                   // N int2
    int*      cur   = (int*)(offse + N);                  // nbin ints

    const int B = 256;
    int nstrip = (N + 15) / 16;            // 6250 GEMM strips (16 nodes/wave)
    int gemmBlocks = (nstrip + 7) / 8;     // 8 waves per 512-thread block
    int gAgg = (N + 15) / 16;              // 16 nodes per block (4 nodes/wave)
    int gN16 = (N * 16 + B - 1) / B;

    hipMemsetAsync(cur, 0, nbin * sizeof(int), stream);
    kFused<<<nblk + gemmBlocks, 512, 0, stream>>>(row, col, ew, cur, tmp,
                                                  x, W1, g, E, nblk, nstrip, N);
    kB<<<nbin, 512, 0, stream>>>(tmp, cur, g, edata, offse, dinv, h, N);
    k_agg_h2<<<gAgg, B, 0, stream>>>(offse, edata, dinv, h, b1, W2, h2p, N);
    k_out<<<gN16, B, 0, stream>>>(offse, edata, dinv, h2p, b2, out, N);
}